// Round 4
// baseline (323.751 us; speedup 1.0000x reference)
//
#include <hip/hip_runtime.h>

#define NCOL 1116
#define NLEV 7
#define NT 256
#define RPB 4          // rows per block, one wave each
#define ARENA 1184     // floats of LDS per row (4736 B)

#define WB() __builtin_amdgcn_wave_barrier()
#define VDRAIN() asm volatile("s_waitcnt vmcnt(0)" ::: "memory")

namespace {
constexpr float DEC_LO[8] = {-0.010597401784997278f,  0.032883011666982945f,
                              0.030841381835986965f, -0.18703481171888114f,
                             -0.02798376941698385f,   0.6308807679295904f,
                              0.7148465705525415f,    0.23037781330885523f};
constexpr float DEC_HI[8] = {-0.23037781330885523f,   0.7148465705525415f,
                             -0.6308807679295904f,   -0.02798376941698385f,
                              0.18703481171888114f,   0.030841381835986965f,
                             -0.032883011666982945f, -0.010597401784997278f};
constexpr float REC_LO[8] = { 0.23037781330885523f,   0.7148465705525415f,
                              0.6308807679295904f,   -0.02798376941698385f,
                             -0.18703481171888114f,   0.030841381835986965f,
                              0.032883011666982945f, -0.010597401784997278f};
constexpr float REC_HI[8] = {-0.010597401784997278f, -0.032883011666982945f,
                              0.030841381835986965f,  0.18703481171888114f,
                             -0.02798376941698385f,  -0.6308807679295904f,
                              0.7148465705525415f,   -0.23037781330885523f};
}

static __device__ __forceinline__ float softf(float c, float t) {
    return copysignf(fmaxf(fabsf(c) - t, 0.0f), c);
}

static __device__ __forceinline__ void dec8(const float* v, float& lo, float& hi) {
    float l = DEC_LO[7] * v[0];
    float h = DEC_HI[7] * v[0];
    #pragma unroll
    for (int s = 6; s >= 0; --s) {
        l = fmaf(DEC_LO[s], v[7 - s], l);
        h = fmaf(DEC_HI[s], v[7 - s], h);
    }
    lo = l; hi = h;
}

static __device__ __forceinline__ float2 rec_pair(float ca0, float ca1, float ca2, float ca3,
                                                  float cd0, float cd1, float cd2, float cd3) {
    float y0 = fmaf(REC_LO[0], ca3, fmaf(REC_LO[2], ca2, fmaf(REC_LO[4], ca1, REC_LO[6] * ca0)));
    y0 = fmaf(REC_HI[0], cd3, fmaf(REC_HI[2], cd2, fmaf(REC_HI[4], cd1, fmaf(REC_HI[6], cd0, y0))));
    float y1 = fmaf(REC_LO[1], ca3, fmaf(REC_LO[3], ca2, fmaf(REC_LO[5], ca1, REC_LO[7] * ca0)));
    y1 = fmaf(REC_HI[1], cd3, fmaf(REC_HI[3], cd2, fmaf(REC_HI[5], cd1, fmaf(REC_HI[7], cd0, y1))));
    return make_float2(y0, y1);
}

// one forward level: nxt[o] = conv_lo, dW[o] = soft(conv_hi)
template<int NOUT, bool SOFT_A>
static __device__ __forceinline__ void fwd_level(const float* __restrict__ cur,
                                                 float* __restrict__ nxt,
                                                 float* __restrict__ dW,
                                                 int lane, float thr) {
    constexpr int K = (NOUT + 63) >> 6;
    constexpr int TAIL = NOUT - ((K - 1) << 6);
    #pragma unroll
    for (int k = 0; k < K; ++k) {
        const int o = lane + (k << 6);
        if (k < K - 1 || lane < TAIL) {
            const float2* p = (const float2*)(cur + 2 * o - 6);
            float2 q0 = p[0], q1 = p[1], q2 = p[2], q3 = p[3];
            float v[8] = {q0.x, q0.y, q1.x, q1.y, q2.x, q2.y, q3.x, q3.y};
            float lo, hi;
            dec8(v, lo, hi);
            nxt[o] = SOFT_A ? softf(lo, thr) : lo;
            dW[o]  = softf(hi, thr);
        }
    }
}

// one inverse level: nxt[0..2(M-3)) from cur (approx, >=M valid) + dp (detail, M valid)
template<int M>
static __device__ __forceinline__ void inv_level(const float* __restrict__ cur,
                                                 const float* __restrict__ dp,
                                                 float* __restrict__ nxt, int lane) {
    constexpr int npair = M - 3;
    constexpr int Qf = npair >> 1;
    constexpr int KI = (Qf + 63) >> 6;
    constexpr int TAILQ = Qf - ((KI - 1) << 6);
    #pragma unroll
    for (int k = 0; k < KI; ++k) {
        const int q = lane + (k << 6);
        if (k < KI - 1 || lane < TAILQ) {
            const int m = q << 1;
            const float2* pa = (const float2*)(cur + m);
            const float2* pd = (const float2*)(dp + m);
            float2 a01 = pa[0], a23 = pa[1];
            float2 d01 = pd[0], d23 = pd[1];
            float ca4 = cur[m + 4], cd4 = dp[m + 4];
            float2 y01 = rec_pair(a01.x, a01.y, a23.x, a23.y, d01.x, d01.y, d23.x, d23.y);
            float2 y23 = rec_pair(a01.y, a23.x, a23.y, ca4, d01.y, d23.x, d23.y, cd4);
            *(float4*)(nxt + 2 * m) = make_float4(y01.x, y01.y, y23.x, y23.y);
        }
    }
    if constexpr (npair & 1) {
        if (lane == 0) {
            const int m = npair - 1;
            float2 y01 = rec_pair(cur[m], cur[m + 1], cur[m + 2], cur[m + 3],
                                  dp[m],  dp[m + 1],  dp[m + 2],  dp[m + 3]);
            *(float2*)(nxt + 2 * m) = y01;
        }
    }
}

static __device__ __forceinline__ void pads(float* base, int nout, int lane) {
    // front 6 zeros, back 8 zeros
    if (lane < 14) { const int j = lane < 6 ? lane - 6 : nout + lane - 6; base[j] = 0.0f; }
}

__global__ __launch_bounds__(NT)
void wavelet_kernel(const float* __restrict__ x,
                    const float* __restrict__ thr_ptr,
                    float* __restrict__ out, int nrow) {
    __shared__ __align__(16) float SH[RPB * ARENA];

    const int lane = threadIdx.x & 63;
    const int wv   = threadIdx.x >> 6;
    const int row  = blockIdx.x * RPB + wv;
    if (row >= nrow) return;                 // wave-uniform, no block barriers used

    const float thr = fmaxf(thr_ptr[0], 0.01f);

    // LDS per row: d0 @0 (561), d5 @562 (24), d6 @586 (15), B data @608 (561; pads 602..607, 1169..1176)
    float* const arena = SH + wv * ARENA;
    float* const lD0 = arena;
    float* const lD5 = arena + 562;
    float* const lD6 = arena + 586;
    float* const lB  = arena + 608;

    // out row doubles as scratch until the final write:
    //   d1 @0 (284), d2 @284 (145), d3 @430 (76), d4 @506 (41)  -> ends 547
    //   C ping-pong data @556 (max 284; front pads 550..555, back pads to <=847)
    float* const orow = out + (size_t)row * NCOL;
    float* const gC   = orow + 556;
    const float* const xrow = x + (size_t)row * NCOL;

    // ---- forward level 0: windows straight from global x ----
    {
        #pragma unroll
        for (int k = 0; k < 9; ++k) {
            const int o = lane + (k << 6);
            if (k < 8 || lane < 49) {
                float v[8];
                bool fast = (k >= 1 && k <= 7);
                if (!fast) fast = (o >= 3 && o <= 557);
                if (fast) {
                    const float2* p = (const float2*)(xrow + 2 * o - 6);
                    float2 q0 = p[0], q1 = p[1], q2 = p[2], q3 = p[3];
                    v[0] = q0.x; v[1] = q0.y; v[2] = q1.x; v[3] = q1.y;
                    v[4] = q2.x; v[5] = q2.y; v[6] = q3.x; v[7] = q3.y;
                } else {
                    #pragma unroll
                    for (int j = 0; j < 8; ++j) {
                        const int idx = 2 * o - 6 + j;
                        v[j] = (idx >= 0 && idx < NCOL) ? xrow[idx] : 0.0f;
                    }
                }
                float lo, hi;
                dec8(v, lo, hi);
                lB[o]  = lo;               // a1 (LDS)
                lD0[o] = softf(hi, thr);   // d0 (LDS)
            }
        }
        pads(lB, 561, lane);
        WB();
    }

    // ---- forward levels 1..6 (a-pingpong alternates LDS B / global C) ----
    fwd_level<284, false>(lB, gC, orow + 0,   lane, thr);  pads(gC, 284, lane); VDRAIN(); WB(); // a2->C, d1
    fwd_level<145, false>(gC, lB, orow + 284, lane, thr);  pads(lB, 145, lane);           WB(); // a3->B, d2
    fwd_level< 76, false>(lB, gC, orow + 430, lane, thr);  pads(gC,  76, lane); VDRAIN(); WB(); // a4->C, d3
    fwd_level< 41, false>(gC, lB, orow + 506, lane, thr);  pads(lB,  41, lane);           WB(); // a5->B, d4
    fwd_level< 24, false>(lB, gC, lD5,        lane, thr);  pads(gC,  24, lane); VDRAIN(); WB(); // a6->C, d5 (LDS)
    fwd_level< 15, true >(gC, lB, lD6,        lane, thr);                                 WB(); // a7->B (soft), d6 (LDS)

    // ---- inverse levels 6..1 ----
    inv_level< 15>(lB, lD6,        gC, lane);  VDRAIN(); WB();   // a6' -> C
    inv_level< 24>(gC, lD5,        lB, lane);            WB();   // a5' -> B
    inv_level< 41>(lB, orow + 506, gC, lane);  VDRAIN(); WB();   // a4' -> C   (d4 drained at F5's VDRAIN)
    inv_level< 76>(gC, orow + 430, lB, lane);            WB();   // a3' -> B
    inv_level<145>(lB, orow + 284, gC, lane);  VDRAIN(); WB();   // a2' -> C
    inv_level<284>(gC, orow + 0,   lB, lane);            WB();   // a1' -> B

    // ---- inverse level 0: read B + d0 (both LDS), write final out float4 ----
    {
        const float* const cur = lB;    // a1' (562 valid, uses 561)
        const float* const dp  = lD0;   // d0
        float4* oq = (float4*)orow;
        #pragma unroll
        for (int k = 0; k < 5; ++k) {   // npair=558 -> 279 quads: 4 full iters + tail 23
            const int q = lane + (k << 6);
            if (k < 4 || lane < 23) {
                const int m = q << 1;
                const float2* pa = (const float2*)(cur + m);
                const float2* pd = (const float2*)(dp + m);
                float2 a01 = pa[0], a23 = pa[1];
                float2 d01 = pd[0], d23 = pd[1];
                float ca4 = cur[m + 4], cd4 = dp[m + 4];
                float2 y01 = rec_pair(a01.x, a01.y, a23.x, a23.y, d01.x, d01.y, d23.x, d23.y);
                float2 y23 = rec_pair(a01.y, a23.x, a23.y, ca4, d01.y, d23.x, d23.y, cd4);
                oq[q] = make_float4(y01.x, y01.y, y23.x, y23.y);
            }
        }
    }
}

extern "C" void kernel_launch(void* const* d_in, const int* in_sizes, int n_in,
                              void* d_out, int out_size, void* d_ws, size_t ws_size,
                              hipStream_t stream) {
    const float* x = (const float*)d_in[0];
    const float* thr = (const float*)d_in[1];
    float* out = (float*)d_out;
    const int nrow = in_sizes[0] / NCOL;
    const int nblk = (nrow + RPB - 1) / RPB;
    hipLaunchKernelGGL(wavelet_kernel, dim3(nblk), dim3(NT), 0, stream, x, thr, out, nrow);
}

// Round 5
// 290.330 us; speedup vs baseline: 1.1151x; 1.1151x over previous
//
#include <hip/hip_runtime.h>

#define NCOL 1116
#define NLEV 7
#define NT 256
#define RPB 4            // rows per block, one wave each
#define D0STRIDE 562     // d0 row stride in d_ws (even => float2-aligned per row)

#define WB() __builtin_amdgcn_wave_barrier()
#define VDRAIN() asm volatile("s_waitcnt vmcnt(0)" ::: "memory")

namespace {
constexpr float DEC_LO[8] = {-0.010597401784997278f,  0.032883011666982945f,
                              0.030841381835986965f, -0.18703481171888114f,
                             -0.02798376941698385f,   0.6308807679295904f,
                              0.7148465705525415f,    0.23037781330885523f};
constexpr float DEC_HI[8] = {-0.23037781330885523f,   0.7148465705525415f,
                             -0.6308807679295904f,   -0.02798376941698385f,
                              0.18703481171888114f,   0.030841381835986965f,
                             -0.032883011666982945f, -0.010597401784997278f};
constexpr float REC_LO[8] = { 0.23037781330885523f,   0.7148465705525415f,
                              0.6308807679295904f,   -0.02798376941698385f,
                             -0.18703481171888114f,   0.030841381835986965f,
                              0.032883011666982945f, -0.010597401784997278f};
constexpr float REC_HI[8] = {-0.010597401784997278f, -0.032883011666982945f,
                              0.030841381835986965f,  0.18703481171888114f,
                             -0.02798376941698385f,  -0.6308807679295904f,
                              0.7148465705525415f,   -0.23037781330885523f};
}

static __device__ __forceinline__ float softf(float c, float t) {
    return copysignf(fmaxf(fabsf(c) - t, 0.0f), c);
}

static __device__ __forceinline__ void dec8(const float* v, float& lo, float& hi) {
    float l = DEC_LO[7] * v[0];
    float h = DEC_HI[7] * v[0];
    #pragma unroll
    for (int s = 6; s >= 0; --s) {
        l = fmaf(DEC_LO[s], v[7 - s], l);
        h = fmaf(DEC_HI[s], v[7 - s], h);
    }
    lo = l; hi = h;
}

static __device__ __forceinline__ float2 rec_pair(float ca0, float ca1, float ca2, float ca3,
                                                  float cd0, float cd1, float cd2, float cd3) {
    float y0 = fmaf(REC_LO[0], ca3, fmaf(REC_LO[2], ca2, fmaf(REC_LO[4], ca1, REC_LO[6] * ca0)));
    y0 = fmaf(REC_HI[0], cd3, fmaf(REC_HI[2], cd2, fmaf(REC_HI[4], cd1, fmaf(REC_HI[6], cd0, y0))));
    float y1 = fmaf(REC_LO[1], ca3, fmaf(REC_LO[3], ca2, fmaf(REC_LO[5], ca1, REC_LO[7] * ca0)));
    y1 = fmaf(REC_HI[1], cd3, fmaf(REC_HI[3], cd2, fmaf(REC_HI[5], cd1, fmaf(REC_HI[7], cd0, y1))));
    return make_float2(y0, y1);
}

template<int NOUT, bool SOFT_A>
static __device__ __forceinline__ void fwd_level(const float* __restrict__ cur,
                                                 float* __restrict__ nxt,
                                                 float* __restrict__ dW,
                                                 int lane, float thr) {
    constexpr int K = (NOUT + 63) >> 6;
    constexpr int TAIL = NOUT - ((K - 1) << 6);
    #pragma unroll
    for (int k = 0; k < K; ++k) {
        const int o = lane + (k << 6);
        if (k < K - 1 || lane < TAIL) {
            const float2* p = (const float2*)(cur + 2 * o - 6);
            float2 q0 = p[0], q1 = p[1], q2 = p[2], q3 = p[3];
            float v[8] = {q0.x, q0.y, q1.x, q1.y, q2.x, q2.y, q3.x, q3.y};
            float lo, hi;
            dec8(v, lo, hi);
            nxt[o] = SOFT_A ? softf(lo, thr) : lo;
            dW[o]  = softf(hi, thr);
        }
    }
}

// inverse level: nxt[0..2(M-3)) from cur (approx) + dp (detail; LDS or global pointer)
template<int M>
static __device__ __forceinline__ void inv_level(const float* __restrict__ cur,
                                                 const float* __restrict__ dp,
                                                 float* __restrict__ nxt, int lane) {
    constexpr int npair = M - 3;
    constexpr int Qf = npair >> 1;
    constexpr int KI = (Qf + 63) >> 6;
    constexpr int TAILQ = Qf - ((KI - 1) << 6);
    #pragma unroll
    for (int k = 0; k < KI; ++k) {
        const int q = lane + (k << 6);
        if (k < KI - 1 || lane < TAILQ) {
            const int m = q << 1;
            const float2* pa = (const float2*)(cur + m);
            const float2* pd = (const float2*)(dp + m);
            float2 a01 = pa[0], a23 = pa[1];
            float2 d01 = pd[0], d23 = pd[1];
            float ca4 = cur[m + 4], cd4 = dp[m + 4];
            float2 y01 = rec_pair(a01.x, a01.y, a23.x, a23.y, d01.x, d01.y, d23.x, d23.y);
            float2 y23 = rec_pair(a01.y, a23.x, a23.y, ca4, d01.y, d23.x, d23.y, cd4);
            *(float4*)(nxt + 2 * m) = make_float4(y01.x, y01.y, y23.x, y23.y);
        }
    }
    if constexpr (npair & 1) {
        if (lane == 0) {
            const int m = npair - 1;
            float2 y01 = rec_pair(cur[m], cur[m + 1], cur[m + 2], cur[m + 3],
                                  dp[m],  dp[m + 1],  dp[m + 2],  dp[m + 3]);
            *(float2*)(nxt + 2 * m) = y01;
        }
    }
}

static __device__ __forceinline__ void pads(float* base, int nout, int lane) {
    if (lane < 14) { const int j = lane < 6 ? lane - 6 : nout + lane - 6; base[j] = 0.0f; }
}

template<bool D0G>   // true: d0 lives in d_ws global scratch; false: d0 in LDS
__global__ __launch_bounds__(NT)
void wavelet_kernel(const float* __restrict__ x,
                    const float* __restrict__ thr_ptr,
                    float* __restrict__ out,
                    float* __restrict__ d0ws, int nrow) {
    // LDS layout (floats, per row): d2..d6 pool, then B and C ping-pong buffers.
    constexpr int D2 = 0, D3 = 146, D4 = 222, D5 = 264, D6 = 288;
    constexpr int D0L  = 304;                    // (only used when !D0G) 562 floats
    constexpr int BDAT = D0G ? 312 : 872;        // 16B-aligned data base, 6 front pads
    constexpr int CDAT = D0G ? 888 : 1448;       // 16B-aligned data base, 6 front pads
    constexpr int ARENA = D0G ? 1184 : 1740;

    __shared__ __align__(16) float SH[RPB * ARENA];

    const int lane = threadIdx.x & 63;
    const int wv   = threadIdx.x >> 6;
    const int row  = blockIdx.x * RPB + wv;
    if (row >= nrow) return;                 // wave-private rows, no block barriers

    const float thr = fmaxf(thr_ptr[0], 0.01f);

    float* const arena = SH + wv * ARENA;
    float* const lB = arena + BDAT;
    float* const c8 = arena + CDAT;
    float* const orow = out + (size_t)row * NCOL;
    const float* const xrow = x + (size_t)row * NCOL;
    float* const d0row = D0G ? (d0ws + (size_t)row * D0STRIDE) : (arena + D0L);

    // ---- F0: x (global) -> a1 (LDS B) + d0 (global scratch / LDS). 2 outputs/lane ----
    #pragma unroll
    for (int k = 0; k < 5; ++k) {
        const int b = lane + (k << 6);
        if (k < 4 || lane <= 24) {            // b <= 280
            float v[10];                       // x[4b-6 .. 4b+3]
            if (b >= 2 && b <= 278) {
                const float2* p = (const float2*)(xrow + 4 * b - 6);
                #pragma unroll
                for (int j = 0; j < 5; ++j) { float2 q = p[j]; v[2*j] = q.x; v[2*j+1] = q.y; }
            } else {
                #pragma unroll
                for (int j = 0; j < 10; ++j) {
                    const int idx = 4 * b - 6 + j;
                    v[j] = (idx >= 0 && idx < NCOL) ? xrow[idx] : 0.0f;
                }
            }
            float lo0, hi0, lo1, hi1;
            dec8(v,     lo0, hi0);            // o = 2b
            dec8(v + 2, lo1, hi1);            // o = 2b+1
            if (b < 280) {
                *(float2*)(lB + 2 * b)    = make_float2(lo0, lo1);
                *(float2*)(d0row + 2 * b) = make_float2(softf(hi0, thr), softf(hi1, thr));
            } else {                          // b == 280: single output o=560
                lB[560]    = lo0;
                d0row[560] = softf(hi0, thr);
            }
        }
    }
    pads(lB, 561, lane);
    WB();

    // ---- F1: a1 (B) -> a2 (C) + d1 -> orow (global scratch; consumed at I1) ----
    #pragma unroll
    for (int k = 0; k < 5; ++k) {             // 284 outputs: 4 full + tail 28
        const int o = lane + (k << 6);
        if (k < 4 || lane < 28) {
            const float2* p = (const float2*)(lB + 2 * o - 6);
            float2 q0 = p[0], q1 = p[1], q2 = p[2], q3 = p[3];
            float v[8] = {q0.x, q0.y, q1.x, q1.y, q2.x, q2.y, q3.x, q3.y};
            float lo, hi;
            dec8(v, lo, hi);
            c8[o]   = lo;
            orow[o] = softf(hi, thr);
        }
    }
    pads(c8, 284, lane);
    WB();

    // ---- F2..F6 (LDS ping-pong; d2..d6 in LDS) ----
    fwd_level<145, false>(c8, lB, arena + D2, lane, thr); pads(lB, 145, lane); WB();
    fwd_level< 76, false>(lB, c8, arena + D3, lane, thr); pads(c8,  76, lane); WB();
    fwd_level< 41, false>(c8, lB, arena + D4, lane, thr); pads(lB,  41, lane); WB();
    fwd_level< 24, false>(lB, c8, arena + D5, lane, thr); pads(c8,  24, lane); WB();
    fwd_level< 15, true >(c8, lB, arena + D6, lane, thr);                      WB();

    // ---- I6..I2 (LDS) ----
    inv_level< 15>(lB, arena + D6, c8, lane); WB();   // a6' -> C
    inv_level< 24>(c8, arena + D5, lB, lane); WB();   // a5' -> B
    inv_level< 41>(lB, arena + D4, c8, lane); WB();   // a4' -> C
    inv_level< 76>(c8, arena + D3, lB, lane); WB();   // a3' -> B
    inv_level<145>(lB, arena + D2, c8, lane); WB();   // a2' -> C

    // ---- I1: a2'(C) + d1 (global, orow) -> a1'(B) ----
    VDRAIN();                                  // d1 (and d0) stores long since landed
    inv_level<284>(c8, orow, lB, lane); WB();

    // ---- I0: a1'(B) + d0 -> final out (float4) ----
    VDRAIN();
    {
        const float* const cur = lB;           // a1' (562 values)
        const float* const dp  = d0row;        // global d_ws or LDS
        float4* oq = (float4*)orow;
        #pragma unroll
        for (int k = 0; k < 5; ++k) {          // 279 quads: 4 full + tail 23
            const int q = lane + (k << 6);
            if (k < 4 || lane < 23) {
                const int m = q << 1;
                const float2* pa = (const float2*)(cur + m);
                const float2* pd = (const float2*)(dp + m);
                float2 a01 = pa[0], a23 = pa[1];
                float2 d01 = pd[0], d23 = pd[1];
                float ca4 = cur[m + 4], cd4 = dp[m + 4];
                float2 y01 = rec_pair(a01.x, a01.y, a23.x, a23.y, d01.x, d01.y, d23.x, d23.y);
                float2 y23 = rec_pair(a01.y, a23.x, a23.y, ca4, d01.y, d23.x, d23.y, cd4);
                oq[q] = make_float4(y01.x, y01.y, y23.x, y23.y);
            }
        }
    }
}

extern "C" void kernel_launch(void* const* d_in, const int* in_sizes, int n_in,
                              void* d_out, int out_size, void* d_ws, size_t ws_size,
                              hipStream_t stream) {
    const float* x = (const float*)d_in[0];
    const float* thr = (const float*)d_in[1];
    float* out = (float*)d_out;
    const int nrow = in_sizes[0] / NCOL;
    const int nblk = (nrow + RPB - 1) / RPB;
    const size_t d0_need = (size_t)nrow * D0STRIDE * sizeof(float);
    if (d_ws != nullptr && ws_size >= d0_need) {
        hipLaunchKernelGGL(wavelet_kernel<true>, dim3(nblk), dim3(NT), 0, stream,
                           x, thr, out, (float*)d_ws, nrow);
    } else {
        hipLaunchKernelGGL(wavelet_kernel<false>, dim3(nblk), dim3(NT), 0, stream,
                           x, thr, out, (float*)d_ws, nrow);
    }
}